// Round 5
// baseline (202.870 us; speedup 1.0000x reference)
//
#include <hip/hip_runtime.h>
#include <hip/hip_bf16.h>
#include <math.h>

#define B_ 4
#define T_ 4096
#define C_ 1024
#define H_ 64
#define ROWS_ (B_*T_)

typedef __attribute__((ext_vector_type(8))) short bf16x8;
typedef __attribute__((ext_vector_type(4))) float f32x4;

__device__ __forceinline__ unsigned short f2bf(float f) {
    union { float f; unsigned u; } x; x.f = f;
    unsigned r = x.u + 0x7fffu + ((x.u >> 16) & 1u);   // RNE
    return (unsigned short)(r >> 16);
}
__device__ __forceinline__ float bf2f(unsigned short s) {
    union { unsigned u; float f; } x; x.u = ((unsigned)s) << 16;
    return x.f;
}
__device__ __forceinline__ unsigned pk2bf(float a, float b) {
    __hip_bfloat162 h = __float22bfloat162_rn(float2{a, b});
    return *reinterpret_cast<unsigned*>(&h);
}

// ---------------------------------------------------------------------------
// Kernel 0: weight prep. w[1024 k][64 n] fp32 -> wt[m][64 n][1024 k] bf16.
// ---------------------------------------------------------------------------
__global__ __launch_bounds__(256) void prep_weights(
    const float* __restrict__ wq, const float* __restrict__ wk,
    const float* __restrict__ wv, unsigned short* __restrict__ wt)
{
    __shared__ float ts[64][68];
    const int m  = blockIdx.x >> 4;
    const int k0 = (blockIdx.x & 15) * 64;
    const float* w = (m == 0) ? wq : (m == 1) ? wk : wv;
    const int tid = threadIdx.x;
    {
        const int r = tid >> 2;
        const int c = (tid & 3) * 16;
        #pragma unroll
        for (int i = 0; i < 4; ++i)
            *reinterpret_cast<float4*>(&ts[r][c + 4*i]) =
                *reinterpret_cast<const float4*>(&w[(size_t)(k0 + r)*H_ + c + 4*i]);
    }
    __syncthreads();
    {
        const int n  = tid >> 2;
        const int kc = (tid & 3) * 16;
        unsigned short outp[16];
        #pragma unroll
        for (int j = 0; j < 16; ++j) outp[j] = f2bf(ts[kc + j][n]);
        unsigned short* dst = &wt[((size_t)m*64 + n)*C_ + k0 + kc];
        *reinterpret_cast<uint4*>(dst)     = *reinterpret_cast<uint4*>(&outp[0]);
        *reinterpret_cast<uint4*>(dst + 8) = *reinterpret_cast<uint4*>(&outp[8]);
    }
}

// ---------------------------------------------------------------------------
// Kernel 1: barrier-free bf16 MFMA QKV projection + fused RoPE.
// Grid 256, 4 waves/block. Wave = one 16-row strip x all 192 cols. A and B
// fragments loaded DIRECTLY from global (x converted fp32->bf16 in-reg; wt
// is L2-resident, L1 dedups across waves). Zero LDS, zero barriers -> the
// compiler pipelines loads across K-steps freely. q scaled by 0.125 here.
// ---------------------------------------------------------------------------
__global__ __launch_bounds__(256) void qkv_mfma_kernel(
    const float* __restrict__ x, const unsigned short* __restrict__ wt,
    unsigned short* __restrict__ qb, unsigned short* __restrict__ kb,
    unsigned short* __restrict__ vtb)
{
    const int tid  = threadIdx.x;
    const int w    = tid >> 6;         // wave = row-tile 0..3
    const int lane = tid & 63;
    const int lr   = lane & 15;
    const int lg   = lane >> 4;
    const int rb   = blockIdx.x * 64;
    const int row  = rb + w*16 + lr;

    const float*          xp = &x[(size_t)row*C_ + lg*8];
    const unsigned short* wp = &wt[(size_t)lr*C_ + lg*8];

    f32x4 acc[12];
    #pragma unroll
    for (int j = 0; j < 12; ++j) acc[j] = f32x4{0.f, 0.f, 0.f, 0.f};

    #pragma unroll 2
    for (int t = 0; t < 16; ++t) {
        #pragma unroll
        for (int kh = 0; kh < 2; ++kh) {
            const float* xq = xp + t*64 + kh*32;
            const float4 a0 = *reinterpret_cast<const float4*>(xq);
            const float4 a1 = *reinterpret_cast<const float4*>(xq + 4);
            union { uint4 u; bf16x8 v; } af;
            af.u.x = pk2bf(a0.x, a0.y);
            af.u.y = pk2bf(a0.z, a0.w);
            af.u.z = pk2bf(a1.x, a1.y);
            af.u.w = pk2bf(a1.z, a1.w);
            #pragma unroll
            for (int j = 0; j < 12; ++j) {
                bf16x8 bf = *reinterpret_cast<const bf16x8*>(
                    wp + (size_t)j*16*C_ + t*64 + kh*32);
                acc[j] = __builtin_amdgcn_mfma_f32_16x16x32_bf16(af.v, bf, acc[j], 0, 0, 0);
            }
        }
    }

    // epilogue: C row = rb + w*16 + lg*4 + i, col = j*16 + lr
    const int row0 = rb + w*16 + lg*4;
    #pragma unroll
    for (int j = 0; j < 12; ++j) {
        const int c = j*16 + lr;
        const int m = c >> 6;
        const int h = c & 63;
        if (m < 2) {
            // inv_freq = 10000^(-(h&~1)/64) = exp2(-(h&~1)*log2(1e4)/64)
            const float inv = __builtin_exp2f(-(float)(h & ~1) *
                                              (13.287712379549449f / 64.f));
            unsigned short* dst = (m == 0) ? qb : kb;
            const float qs = (m == 0) ? 0.125f : 1.0f;   // fold softmax scale
            #pragma unroll
            for (int i = 0; i < 4; ++i) {
                const float v  = acc[j][i];
                const float pr = __shfl_xor(v, 1);
                const int  r   = row0 + i;
                const int  tp  = r & (T_ - 1);
                float sn, cs;
                sincosf((float)tp * inv, &sn, &cs);
                if (!(h & 1)) {
                    const float oe = (v*cs - pr*sn) * qs;
                    const float oo = (v*sn + pr*cs) * qs;
                    *reinterpret_cast<unsigned*>(&dst[(size_t)r*H_ + h]) =
                        pk2bf(oe, oo);
                }
            }
        } else {
            const int bh = (row0 >> 12)*64 + h;
            const int tp = row0 & (T_ - 1);
            unsigned short pk[4];
            #pragma unroll
            for (int i = 0; i < 4; ++i) pk[i] = f2bf(acc[j][i]);
            *reinterpret_cast<uint2*>(&vtb[(size_t)bh*T_ + tp]) =
                *reinterpret_cast<uint2*>(pk);
        }
    }
}

// ---------------------------------------------------------------------------
// Kernel 2: barrier-free split-K flash attention. Work unit = (b, q-tile of
// 64 rows, chunk of CH k-tiles). 4 waves/block, wave owns 16 q-rows. K and
// V^T fragments loaded directly from global (L2-resident); only P makes an
// LDS round-trip (per-wave, no cross-wave sync). Zero __syncthreads.
// Chunk count per qt = qt/CH + 1; group g=qt/CH starts at (CH/2)*g*(g+1).
// ---------------------------------------------------------------------------
__global__ __launch_bounds__(256, 4) void attn_chunk_kernel(
    const unsigned short* __restrict__ qb, const unsigned short* __restrict__ kb,
    const unsigned short* __restrict__ vtb,
    unsigned short* __restrict__ partO, float* __restrict__ partML,
    int CH, int per_batch)
{
    __shared__ unsigned short Pls[4][1024];

    const int tid  = threadIdx.x;
    const int w    = tid >> 6;
    const int lane = tid & 63;
    const int lr   = lane & 15;
    const int lg   = lane >> 4;

    const int cid = blockIdx.x;
    const int b   = cid / per_batch;
    int r0 = cid - b*per_batch;
    int g = 0, off = 0;
    while (r0 >= off + CH*(g + 1)) { off += CH*(g + 1); ++g; }
    const int idx = r0 - off;
    const int qt  = g*CH + idx/(g + 1);
    const int c   = idx % (g + 1);

    const int q0  = qt * 64;
    const int kt0 = c * CH;
    const int ns  = min(kt0 + CH, qt + 1) - kt0;
    const size_t rbase = (size_t)b * T_;

    char* Pw = (char*)&Pls[w][0];

    // Q fragment (B-operand: col=lane&15 -> q-row, k=(lane>>4)*8+j -> d)
    bf16x8 qf[2];
    {
        const unsigned short* qp = qb + (rbase + q0 + w*16 + lr)*H_ + lg*8;
        qf[0] = *reinterpret_cast<const bf16x8*>(qp);
        qf[1] = *reinterpret_cast<const bf16x8*>(qp + 32);
    }

    float mrow = -1e30f, lrow = 0.f;
    f32x4 acc[4];
    #pragma unroll
    for (int hs = 0; hs < 4; ++hs) acc[hs] = f32x4{0.f, 0.f, 0.f, 0.f};

    const unsigned short* kp = kb + (rbase + (size_t)kt0*64 + lr)*H_ + lg*8;
    const unsigned short* vp[4];
    #pragma unroll
    for (int hs = 0; hs < 4; ++hs)
        vp[hs] = vtb + ((size_t)(b*64 + hs*16 + lr))*T_ + (size_t)kt0*64 + lg*8;

    for (int s = 0; s < ns; ++s) {
        const int kt = kt0 + s;

        // ---- S^T = K Q^T, fragments straight from global ----
        f32x4 st[4];
        #pragma unroll
        for (int ks = 0; ks < 4; ++ks) {
            const unsigned short* kr = kp + ((size_t)s*64 + ks*16)*H_;
            bf16x8 kf0 = *reinterpret_cast<const bf16x8*>(kr);
            bf16x8 kf1 = *reinterpret_cast<const bf16x8*>(kr + 32);
            f32x4 t = {0.f, 0.f, 0.f, 0.f};
            t = __builtin_amdgcn_mfma_f32_16x16x32_bf16(kf0, qf[0], t, 0, 0, 0);
            t = __builtin_amdgcn_mfma_f32_16x16x32_bf16(kf1, qf[1], t, 0, 0, 0);
            st[ks] = t;
        }

        // ---- online softmax; mask only on the diagonal tile ----
        const int qg = q0 + w*16 + lr;
        float mx = -1e30f;
        if (kt == qt) {
            #pragma unroll
            for (int ks = 0; ks < 4; ++ks)
                #pragma unroll
                for (int i = 0; i < 4; ++i) {
                    const int kg = kt*64 + ks*16 + lg*4 + i;
                    const float v = (kg <= qg) ? st[ks][i] : -1e30f;
                    st[ks][i] = v;
                    mx = fmaxf(mx, v);
                }
        } else {
            #pragma unroll
            for (int ks = 0; ks < 4; ++ks)
                #pragma unroll
                for (int i = 0; i < 4; ++i) mx = fmaxf(mx, st[ks][i]);
        }
        mx = fmaxf(mx, __shfl_xor(mx, 16));
        mx = fmaxf(mx, __shfl_xor(mx, 32));
        const float mn  = fmaxf(mrow, mx);
        const float scl = __expf(mrow - mn);
        float ls = 0.f;
        #pragma unroll
        for (int ks = 0; ks < 4; ++ks)
            #pragma unroll
            for (int i = 0; i < 4; ++i) {
                const float p = __expf(st[ks][i] - mn);
                st[ks][i] = p;
                ls += p;
            }
        ls += __shfl_xor(ls, 16);
        ls += __shfl_xor(ls, 32);
        lrow = lrow*scl + ls;
        mrow = mn;

        // ---- P -> bf16 -> per-wave LDS (A-operand transpose), no barrier ----
        const int swp = (lr & 7) << 4;
        #pragma unroll
        for (int ks = 0; ks < 4; ++ks) {
            const unsigned u0 = pk2bf(st[ks][0], st[ks][1]);
            const unsigned u1 = pk2bf(st[ks][2], st[ks][3]);
            *reinterpret_cast<uint2*>(Pw + lr*128 + ((ks*32 + lg*8) ^ swp)) =
                make_uint2(u0, u1);
        }

        // ---- rescale O ----
        float sclr[4];
        #pragma unroll
        for (int i = 0; i < 4; ++i) sclr[i] = __shfl(scl, lg*4 + i);
        #pragma unroll
        for (int hs = 0; hs < 4; ++hs)
            #pragma unroll
            for (int i = 0; i < 4; ++i) acc[hs][i] *= sclr[i];

        // ---- O += P V, V^T fragments straight from global ----
        bf16x8 pf0 = *reinterpret_cast<const bf16x8*>(Pw + lr*128 + ((lg*16     ) ^ swp));
        bf16x8 pf1 = *reinterpret_cast<const bf16x8*>(Pw + lr*128 + ((lg*16 + 64) ^ swp));
        #pragma unroll
        for (int hs = 0; hs < 4; ++hs) {
            bf16x8 vf0 = *reinterpret_cast<const bf16x8*>(vp[hs] + s*64);
            bf16x8 vf1 = *reinterpret_cast<const bf16x8*>(vp[hs] + s*64 + 32);
            acc[hs] = __builtin_amdgcn_mfma_f32_16x16x32_bf16(pf0, vf0, acc[hs], 0, 0, 0);
            acc[hs] = __builtin_amdgcn_mfma_f32_16x16x32_bf16(pf1, vf1, acc[hs], 0, 0, 0);
        }
    }

    // ---- write partial: m,l fp32 + un-normalized O bf16 ----
    const int myrow = w*16 + lr;
    if (lg == 0) {
        partML[(size_t)cid*128 + myrow]      = mrow;
        partML[(size_t)cid*128 + 64 + myrow] = lrow;
    }
    #pragma unroll
    for (int hs = 0; hs < 4; ++hs)
        #pragma unroll
        for (int i = 0; i < 4; ++i)
            partO[(size_t)cid*4096 + (size_t)(w*16 + lg*4 + i)*64 + hs*16 + lr] =
                f2bf(acc[hs][i]);
}

// ---------------------------------------------------------------------------
// Kernel 3: combine partials per (b, q-tile). 256 blocks x 256 threads.
// ---------------------------------------------------------------------------
__global__ __launch_bounds__(256) void combine_kernel(
    const unsigned short* __restrict__ partO, const float* __restrict__ partML,
    float* __restrict__ out, int CH, int per_batch)
{
    const int bq = blockIdx.x;
    const int b  = bq >> 6;
    const int qt = bq & 63;
    const int g  = qt / CH;
    const int nc = g + 1;
    const int cb = b*per_batch + (CH/2)*g*(g + 1) + (qt - g*CH)*(g + 1);

    const int tid = threadIdx.x;
    const int row = tid >> 2;
    const int h0  = (tid & 3) * 16;

    float mi[8], wi[8];
    float M = -1e30f;
    #pragma unroll
    for (int i = 0; i < 8; ++i) if (i < nc) {
        mi[i] = partML[(size_t)(cb + i)*128 + row];
        M = fmaxf(M, mi[i]);
    }
    float L = 0.f;
    #pragma unroll
    for (int i = 0; i < 8; ++i) if (i < nc) {
        wi[i] = __expf(mi[i] - M);
        L += partML[(size_t)(cb + i)*128 + 64 + row] * wi[i];
    }
    const float inv = 1.f / L;

    float o[16];
    #pragma unroll
    for (int j = 0; j < 16; ++j) o[j] = 0.f;
    #pragma unroll
    for (int i = 0; i < 8; ++i) if (i < nc) {
        const unsigned short* p = &partO[(size_t)(cb + i)*4096 + (size_t)row*64 + h0];
        uint4 u0 = *reinterpret_cast<const uint4*>(p);
        uint4 u1 = *reinterpret_cast<const uint4*>(p + 8);
        const unsigned* uu = (const unsigned*)&u0;
        #pragma unroll
        for (int j = 0; j < 4; ++j) {
            o[2*j]   += bf2f((unsigned short)(uu[j] & 0xffffu)) * wi[i];
            o[2*j+1] += bf2f((unsigned short)(uu[j] >> 16))     * wi[i];
        }
        const unsigned* uv = (const unsigned*)&u1;
        #pragma unroll
        for (int j = 0; j < 4; ++j) {
            o[8+2*j]   += bf2f((unsigned short)(uv[j] & 0xffffu)) * wi[i];
            o[8+2*j+1] += bf2f((unsigned short)(uv[j] >> 16))     * wi[i];
        }
    }
    float* op = &out[((size_t)b*T_ + (size_t)qt*64 + row)*H_ + h0];
    #pragma unroll
    for (int j = 0; j < 4; ++j) {
        float4 v = make_float4(o[4*j]*inv, o[4*j+1]*inv, o[4*j+2]*inv, o[4*j+3]*inv);
        *reinterpret_cast<float4*>(op + 4*j) = v;
    }
}

// ---------------------------------------------------------------------------
extern "C" void kernel_launch(void* const* d_in, const int* in_sizes, int n_in,
                              void* d_out, int out_size, void* d_ws, size_t ws_size,
                              hipStream_t stream) {
    const float* x  = (const float*)d_in[0];
    const float* wq = (const float*)d_in[1];
    const float* wk = (const float*)d_in[2];
    const float* wv = (const float*)d_in[3];
    float* out = (float*)d_out;

    unsigned short* qb  = (unsigned short*)d_ws;                   // 2MB
    unsigned short* kb  = qb  + (size_t)ROWS_ * H_;                // 2MB
    unsigned short* vtb = kb  + (size_t)ROWS_ * H_;                // 2MB
    unsigned short* wt  = vtb + (size_t)ROWS_ * H_;                // 384KB

    // chunk size: prefer CH=8 (1152 blocks) if workspace allows, else CH=16
    const size_t fixed = (size_t)3*ROWS_*H_*2 + (size_t)3*64*C_*2;
    const size_t need8 = fixed + (size_t)1152*4096*2 + (size_t)1152*128*4;
    int CH, per_batch;
    if (ws_size >= need8) { CH = 8;  per_batch = 288; }
    else                  { CH = 16; per_batch = 160; }
    const int nblk = 4 * per_batch;

    unsigned short* partO  = wt + (size_t)3*64*C_;
    float*          partML = (float*)(partO + (size_t)nblk*4096);

    prep_weights<<<48, 256, 0, stream>>>(wq, wk, wv, wt);
    qkv_mfma_kernel<<<ROWS_/64, 256, 0, stream>>>(x, wt, qb, kb, vtb);
    attn_chunk_kernel<<<nblk, 256, 0, stream>>>(qb, kb, vtb, partO, partML,
                                                CH, per_batch);
    combine_kernel<<<256, 256, 0, stream>>>(partO, partML, out, CH, per_batch);
}

// Round 6
// 142.430 us; speedup vs baseline: 1.4243x; 1.4243x over previous
//
#include <hip/hip_runtime.h>
#include <hip/hip_bf16.h>
#include <math.h>

#define B_ 4
#define T_ 4096
#define C_ 1024
#define H_ 64
#define ROWS_ (B_*T_)

typedef __attribute__((ext_vector_type(8))) short bf16x8;
typedef __attribute__((ext_vector_type(4))) float f32x4;

__device__ __forceinline__ unsigned short f2bf(float f) {
    union { float f; unsigned u; } x; x.f = f;
    unsigned r = x.u + 0x7fffu + ((x.u >> 16) & 1u);   // RNE
    return (unsigned short)(r >> 16);
}
__device__ __forceinline__ float bf2f(unsigned short s) {
    union { unsigned u; float f; } x; x.u = ((unsigned)s) << 16;
    return x.f;
}
__device__ __forceinline__ unsigned pk2bf(float a, float b) {
    __hip_bfloat162 h = __float22bfloat162_rn(float2{a, b});
    return *reinterpret_cast<unsigned*>(&h);
}

// ---------------------------------------------------------------------------
// Kernel 0: weight prep. w[1024 k][64 n] fp32 -> wt[m][64 n][1024 k] bf16.
// ---------------------------------------------------------------------------
__global__ __launch_bounds__(256) void prep_weights(
    const float* __restrict__ wq, const float* __restrict__ wk,
    const float* __restrict__ wv, unsigned short* __restrict__ wt)
{
    __shared__ float ts[64][68];
    const int m  = blockIdx.x >> 4;
    const int k0 = (blockIdx.x & 15) * 64;
    const float* w = (m == 0) ? wq : (m == 1) ? wk : wv;
    const int tid = threadIdx.x;
    {
        const int r = tid >> 2;
        const int c = (tid & 3) * 16;
        #pragma unroll
        for (int i = 0; i < 4; ++i)
            *reinterpret_cast<float4*>(&ts[r][c + 4*i]) =
                *reinterpret_cast<const float4*>(&w[(size_t)(k0 + r)*H_ + c + 4*i]);
    }
    __syncthreads();
    {
        const int n  = tid >> 2;
        const int kc = (tid & 3) * 16;
        unsigned short outp[16];
        #pragma unroll
        for (int j = 0; j < 16; ++j) outp[j] = f2bf(ts[kc + j][n]);
        unsigned short* dst = &wt[((size_t)m*64 + n)*C_ + k0 + kc];
        *reinterpret_cast<uint4*>(dst)     = *reinterpret_cast<uint4*>(&outp[0]);
        *reinterpret_cast<uint4*>(dst + 8) = *reinterpret_cast<uint4*>(&outp[8]);
    }
}

// ---------------------------------------------------------------------------
// Kernel 1: bf16 MFMA QKV projection + fused RoPE. LDS-staged (round-3
// structure) but BM=32 / grid 512 / 256 threads: LDS 28KB -> 5 blocks/CU,
// so other blocks' waves hide each block's barrier + HBM-load waits.
// q scaled by 0.125 (softmax scale folded).
// ---------------------------------------------------------------------------
__global__ __launch_bounds__(256) void qkv_mfma_kernel(
    const float* __restrict__ x, const unsigned short* __restrict__ wt,
    unsigned short* __restrict__ qb, unsigned short* __restrict__ kb,
    unsigned short* __restrict__ vtb)
{
    __shared__ unsigned short As[32*64];     // [row][k] swizzled, 128B rows
    __shared__ unsigned short Ws[192*64];    // [n][k]  swizzled, 128B rows

    const int tid  = threadIdx.x;
    const int w    = tid >> 6;
    const int lane = tid & 63;
    const int rt   = w >> 1;                 // row-tile 0..1
    const int ch   = w & 1;                  // col-half 0..1
    const int lr   = lane & 15;
    const int lg   = lane >> 4;
    const int rb   = blockIdx.x * 32;

    const int ar = tid >> 3;                 // x row 0..31
    const int ac = (tid & 7) * 8;            // fp32 elem col

    float4 axr[2];
    uint4  wvr[6];

    auto load_A = [&](int t) {
        const float* p = &x[(size_t)(rb + ar)*C_ + t*64 + ac];
        axr[0] = *reinterpret_cast<const float4*>(p);
        axr[1] = *reinterpret_cast<const float4*>(p + 4);
    };
    auto load_W = [&](int t) {
        #pragma unroll
        for (int s = 0; s < 6; ++s) {
            const int slot = s*256 + tid;
            const int r    = slot >> 3;      // n-row 0..191
            const int c8   = (slot & 7) * 8;
            wvr[s] = *reinterpret_cast<const uint4*>(&wt[(size_t)r*C_ + t*64 + c8]);
        }
    };
    auto write_A = [&]() {
        unsigned tmp[4];
        tmp[0] = pk2bf(axr[0].x, axr[0].y);
        tmp[1] = pk2bf(axr[0].z, axr[0].w);
        tmp[2] = pk2bf(axr[1].x, axr[1].y);
        tmp[3] = pk2bf(axr[1].z, axr[1].w);
        const int off = ar*128 + ((ac*2) ^ ((ar & 7) << 4));
        *reinterpret_cast<uint4*>((char*)As + off) = *reinterpret_cast<uint4*>(tmp);
    };
    auto write_W = [&]() {
        #pragma unroll
        for (int s = 0; s < 6; ++s) {
            const int slot = s*256 + tid;
            const int r    = slot >> 3;
            const int cb   = (slot & 7) * 16;
            *reinterpret_cast<uint4*>((char*)Ws + r*128 + (cb ^ ((r & 7) << 4))) = wvr[s];
        }
    };

    f32x4 acc[6];
    #pragma unroll
    for (int j = 0; j < 6; ++j) acc[j] = f32x4{0.f, 0.f, 0.f, 0.f};

    load_A(0); load_W(0);
    for (int t = 0; t < 16; ++t) {
        __syncthreads();                     // LDS consumers of step t-1 done
        write_A(); write_W();
        __syncthreads();                     // tiles visible
        if (t < 15) { load_A(t + 1); load_W(t + 1); }   // in flight over compute
        #pragma unroll
        for (int kh = 0; kh < 2; ++kh) {
            const int arow = rt*16 + lr;
            bf16x8 af = *reinterpret_cast<const bf16x8*>(
                (char*)As + arow*128 + ((kh*64 + lg*16) ^ ((arow & 7) << 4)));
            __builtin_amdgcn_s_setprio(1);
            #pragma unroll
            for (int j = 0; j < 6; ++j) {
                const int n = ch*96 + j*16 + lr;
                bf16x8 bf = *reinterpret_cast<const bf16x8*>(
                    (char*)Ws + n*128 + ((kh*64 + lg*16) ^ ((n & 7) << 4)));
                acc[j] = __builtin_amdgcn_mfma_f32_16x16x32_bf16(af, bf, acc[j], 0, 0, 0);
            }
            __builtin_amdgcn_s_setprio(0);
        }
    }

    // epilogue: C row = rb + rt*16 + lg*4 + i, col = ch*96 + j*16 + lr
    const int row0 = rb + rt*16 + lg*4;
    #pragma unroll
    for (int j = 0; j < 6; ++j) {
        const int c = ch*96 + j*16 + lr;     // 0..191
        const int m = c >> 6;
        const int h = c & 63;
        if (m < 2) {
            const float inv = __builtin_exp2f(-(float)(h & ~1) *
                                              (13.287712379549449f / 64.f));
            unsigned short* dst = (m == 0) ? qb : kb;
            const float qs = (m == 0) ? 0.125f : 1.0f;
            #pragma unroll
            for (int i = 0; i < 4; ++i) {
                const float v  = acc[j][i];
                const float pr = __shfl_xor(v, 1);
                const int  r   = row0 + i;
                const int  tp  = r & (T_ - 1);
                float sn, cs;
                sincosf((float)tp * inv, &sn, &cs);
                if (!(h & 1)) {
                    const float oe = (v*cs - pr*sn) * qs;
                    const float oo = (v*sn + pr*cs) * qs;
                    *reinterpret_cast<unsigned*>(&dst[(size_t)r*H_ + h]) =
                        pk2bf(oe, oo);
                }
            }
        } else {
            const int bh = (row0 >> 12)*64 + h;
            const int tp = row0 & (T_ - 1);
            unsigned short pk[4];
            #pragma unroll
            for (int i = 0; i < 4; ++i) pk[i] = f2bf(acc[j][i]);
            *reinterpret_cast<uint2*>(&vtb[(size_t)bh*T_ + tp]) =
                *reinterpret_cast<uint2*>(pk);
        }
    }
}

// ---------------------------------------------------------------------------
// Kernel 2: uniform-chunk split-K flash attention (round-4 LDS structure).
// Work unit = (b, q-tile of 64 rows, chunk of CH k-tiles). 4 waves/block,
// LDS 40KB -> 4 blocks/CU. Double-buffered K/V, one barrier per step.
// setprio(1) around MFMA clusters (T5). Emits partial (m,l fp32; O bf16).
// ---------------------------------------------------------------------------
__global__ __launch_bounds__(256) void attn_chunk_kernel(
    const unsigned short* __restrict__ qb, const unsigned short* __restrict__ kb,
    const unsigned short* __restrict__ vtb,
    unsigned short* __restrict__ partO, float* __restrict__ partML,
    int CH, int per_batch)
{
    __shared__ unsigned short Kls[2][4096];
    __shared__ unsigned short Vls[2][4096];
    __shared__ unsigned short Pls[4][1024];

    const int tid  = threadIdx.x;
    const int w    = tid >> 6;       // wave 0..3, owns q-rows w*16..+15
    const int lane = tid & 63;
    const int lr   = lane & 15;
    const int lg   = lane >> 4;

    const int cid = blockIdx.x;
    const int b   = cid / per_batch;
    int r0 = cid - b*per_batch;
    int g = 0, off = 0;
    while (r0 >= off + CH*(g + 1)) { off += CH*(g + 1); ++g; }
    const int idx = r0 - off;
    const int qt  = g*CH + idx/(g + 1);
    const int c   = idx % (g + 1);

    const int q0  = qt * 64;
    const int kt0 = c * CH;
    const int ns  = min(kt0 + CH, qt + 1) - kt0;
    const size_t rbase = (size_t)b * T_;

    char* Pw = (char*)&Pls[w][0];

    // Q fragment (B-operand: col=lane&15 -> q-row, k=(lane>>4)*8+j -> d)
    bf16x8 qf[2];
    {
        const unsigned short* qp = qb + (rbase + q0 + w*16 + lr)*H_ + lg*8;
        qf[0] = *reinterpret_cast<const bf16x8*>(qp);
        qf[1] = *reinterpret_cast<const bf16x8*>(qp + 32);
    }

    float mrow = -1e30f, lrow = 0.f;
    f32x4 acc[4];
    #pragma unroll
    for (int hs = 0; hs < 4; ++hs) acc[hs] = f32x4{0.f, 0.f, 0.f, 0.f};

    // staging: 256 threads, each 2x16B per matrix
    const int srow = tid >> 3;           // 0..31
    const int scol = (tid & 7) * 8;      // bf16 elems
    uint4 kst[2], vst[2];
    auto issue_loads = [&](int kt) {
        #pragma unroll
        for (int s = 0; s < 2; ++s) {
            const int r = s*32 + srow;
            kst[s] = *reinterpret_cast<const uint4*>(
                &kb[(rbase + (size_t)kt*64 + r)*H_ + scol]);
            vst[s] = *reinterpret_cast<const uint4*>(
                &vtb[((size_t)(b*64 + r))*T_ + (size_t)kt*64 + scol]);
        }
    };
    auto write_lds = [&](int buf) {
        #pragma unroll
        for (int s = 0; s < 2; ++s) {
            const int r   = s*32 + srow;
            const int off2 = r*128 + ((scol*2) ^ ((r & 7) << 4));
            *reinterpret_cast<uint4*>((char*)&Kls[buf][0] + off2) = kst[s];
            *reinterpret_cast<uint4*>((char*)&Vls[buf][0] + off2) = vst[s];
        }
    };

    issue_loads(kt0);
    write_lds(0);

    for (int s = 0; s < ns; ++s) {
        __syncthreads();                       // buffer s&1 visible
        if (s + 1 < ns) issue_loads(kt0 + s + 1);
        const int kt = kt0 + s;
        char* Kb = (char*)&Kls[s & 1][0];
        char* Vb = (char*)&Vls[s & 1][0];

        // S^T = K Q^T
        f32x4 st[4];
        __builtin_amdgcn_s_setprio(1);
        #pragma unroll
        for (int ks = 0; ks < 4; ++ks) {
            const int rr2 = ks*16 + lr;
            const int sw  = (rr2 & 7) << 4;
            bf16x8 kf0 = *reinterpret_cast<const bf16x8*>(Kb + rr2*128 + ((lg*16     ) ^ sw));
            bf16x8 kf1 = *reinterpret_cast<const bf16x8*>(Kb + rr2*128 + ((lg*16 + 64) ^ sw));
            f32x4 t = {0.f, 0.f, 0.f, 0.f};
            t = __builtin_amdgcn_mfma_f32_16x16x32_bf16(kf0, qf[0], t, 0, 0, 0);
            t = __builtin_amdgcn_mfma_f32_16x16x32_bf16(kf1, qf[1], t, 0, 0, 0);
            st[ks] = t;
        }
        __builtin_amdgcn_s_setprio(0);

        // mask + online softmax (lane owns q-row q0 + w*16 + lr)
        const int qg = q0 + w*16 + lr;
        float mx = -1e30f;
        if (kt == qt) {
            #pragma unroll
            for (int ks = 0; ks < 4; ++ks)
                #pragma unroll
                for (int i = 0; i < 4; ++i) {
                    const int kg = kt*64 + ks*16 + lg*4 + i;
                    const float v = (kg <= qg) ? st[ks][i] : -1e30f;
                    st[ks][i] = v;
                    mx = fmaxf(mx, v);
                }
        } else {
            #pragma unroll
            for (int ks = 0; ks < 4; ++ks)
                #pragma unroll
                for (int i = 0; i < 4; ++i) mx = fmaxf(mx, st[ks][i]);
        }
        mx = fmaxf(mx, __shfl_xor(mx, 16));
        mx = fmaxf(mx, __shfl_xor(mx, 32));
        const float mn  = fmaxf(mrow, mx);
        const float scl = __expf(mrow - mn);
        float ls = 0.f;
        #pragma unroll
        for (int ks = 0; ks < 4; ++ks)
            #pragma unroll
            for (int i = 0; i < 4; ++i) {
                const float p = __expf(st[ks][i] - mn);
                st[ks][i] = p;
                ls += p;
            }
        ls += __shfl_xor(ls, 16);
        ls += __shfl_xor(ls, 32);
        lrow = lrow*scl + ls;
        mrow = mn;

        // P -> bf16 -> per-wave LDS (A-operand transpose), no barrier needed
        const int swp = (lr & 7) << 4;
        #pragma unroll
        for (int ks = 0; ks < 4; ++ks) {
            const unsigned u0 = pk2bf(st[ks][0], st[ks][1]);
            const unsigned u1 = pk2bf(st[ks][2], st[ks][3]);
            *reinterpret_cast<uint2*>(Pw + lr*128 + ((ks*32 + lg*8) ^ swp)) =
                make_uint2(u0, u1);
        }

        // rescale O
        float sclr[4];
        #pragma unroll
        for (int i = 0; i < 4; ++i) sclr[i] = __shfl(scl, lg*4 + i);
        #pragma unroll
        for (int hs = 0; hs < 4; ++hs)
            #pragma unroll
            for (int i = 0; i < 4; ++i) acc[hs][i] *= sclr[i];

        // O += P V
        bf16x8 pf0 = *reinterpret_cast<const bf16x8*>(Pw + lr*128 + ((lg*16     ) ^ swp));
        bf16x8 pf1 = *reinterpret_cast<const bf16x8*>(Pw + lr*128 + ((lg*16 + 64) ^ swp));
        __builtin_amdgcn_s_setprio(1);
        #pragma unroll
        for (int hs = 0; hs < 4; ++hs) {
            const int rv  = hs*16 + lr;
            const int swv = (rv & 7) << 4;
            bf16x8 vf0 = *reinterpret_cast<const bf16x8*>(Vb + rv*128 + ((lg*16     ) ^ swv));
            bf16x8 vf1 = *reinterpret_cast<const bf16x8*>(Vb + rv*128 + ((lg*16 + 64) ^ swv));
            acc[hs] = __builtin_amdgcn_mfma_f32_16x16x32_bf16(pf0, vf0, acc[hs], 0, 0, 0);
            acc[hs] = __builtin_amdgcn_mfma_f32_16x16x32_bf16(pf1, vf1, acc[hs], 0, 0, 0);
        }
        __builtin_amdgcn_s_setprio(0);

        if (s + 1 < ns) write_lds((s + 1) & 1);
    }

    // write partial: m,l fp32 + un-normalized O bf16
    const int myrow = w*16 + lr;
    if (lg == 0) {
        partML[(size_t)cid*128 + myrow]      = mrow;
        partML[(size_t)cid*128 + 64 + myrow] = lrow;
    }
    #pragma unroll
    for (int hs = 0; hs < 4; ++hs)
        #pragma unroll
        for (int i = 0; i < 4; ++i)
            partO[(size_t)cid*4096 + (size_t)(w*16 + lg*4 + i)*64 + hs*16 + lr] =
                f2bf(acc[hs][i]);
}

// ---------------------------------------------------------------------------
// Kernel 3: combine partials per (b, q-tile). 256 blocks x 256 threads.
// ---------------------------------------------------------------------------
__global__ __launch_bounds__(256) void combine_kernel(
    const unsigned short* __restrict__ partO, const float* __restrict__ partML,
    float* __restrict__ out, int CH, int per_batch)
{
    const int bq = blockIdx.x;
    const int b  = bq >> 6;
    const int qt = bq & 63;
    const int g  = qt / CH;
    const int nc = g + 1;
    const int cb = b*per_batch + (CH/2)*g*(g + 1) + (qt - g*CH)*(g + 1);

    const int tid = threadIdx.x;
    const int row = tid >> 2;
    const int h0  = (tid & 3) * 16;

    float mi[8], wi[8];
    float M = -1e30f;
    #pragma unroll
    for (int i = 0; i < 8; ++i) if (i < nc) {
        mi[i] = partML[(size_t)(cb + i)*128 + row];
        M = fmaxf(M, mi[i]);
    }
    float L = 0.f;
    #pragma unroll
    for (int i = 0; i < 8; ++i) if (i < nc) {
        wi[i] = __expf(mi[i] - M);
        L += partML[(size_t)(cb + i)*128 + 64 + row] * wi[i];
    }
    const float inv = 1.f / L;

    float o[16];
    #pragma unroll
    for (int j = 0; j < 16; ++j) o[j] = 0.f;
    #pragma unroll
    for (int i = 0; i < 8; ++i) if (i < nc) {
        const unsigned short* p = &partO[(size_t)(cb + i)*4096 + (size_t)row*64 + h0];
        uint4 u0 = *reinterpret_cast<const uint4*>(p);
        uint4 u1 = *reinterpret_cast<const uint4*>(p + 8);
        const unsigned* uu = (const unsigned*)&u0;
        #pragma unroll
        for (int j = 0; j < 4; ++j) {
            o[2*j]   += bf2f((unsigned short)(uu[j] & 0xffffu)) * wi[i];
            o[2*j+1] += bf2f((unsigned short)(uu[j] >> 16))     * wi[i];
        }
        const unsigned* uv = (const unsigned*)&u1;
        #pragma unroll
        for (int j = 0; j < 4; ++j) {
            o[8+2*j]   += bf2f((unsigned short)(uv[j] & 0xffffu)) * wi[i];
            o[8+2*j+1] += bf2f((unsigned short)(uv[j] >> 16))     * wi[i];
        }
    }
    float* op = &out[((size_t)b*T_ + (size_t)qt*64 + row)*H_ + h0];
    #pragma unroll
    for (int j = 0; j < 4; ++j) {
        float4 v = make_float4(o[4*j]*inv, o[4*j+1]*inv, o[4*j+2]*inv, o[4*j+3]*inv);
        *reinterpret_cast<float4*>(op + 4*j) = v;
    }
}

// ---------------------------------------------------------------------------
extern "C" void kernel_launch(void* const* d_in, const int* in_sizes, int n_in,
                              void* d_out, int out_size, void* d_ws, size_t ws_size,
                              hipStream_t stream) {
    const float* x  = (const float*)d_in[0];
    const float* wq = (const float*)d_in[1];
    const float* wk = (const float*)d_in[2];
    const float* wv = (const float*)d_in[3];
    float* out = (float*)d_out;

    unsigned short* qb  = (unsigned short*)d_ws;                   // 2MB
    unsigned short* kb  = qb  + (size_t)ROWS_ * H_;                // 2MB
    unsigned short* vtb = kb  + (size_t)ROWS_ * H_;                // 2MB
    unsigned short* wt  = vtb + (size_t)ROWS_ * H_;                // 384KB

    // chunk size: prefer CH=8 (grid 1152) if workspace allows, else CH=16
    const size_t fixed = (size_t)3*ROWS_*H_*2 + (size_t)3*64*C_*2;
    const size_t need8 = fixed + (size_t)1152*4096*2 + (size_t)1152*128*4;
    int CH, per_batch;
    if (ws_size >= need8) { CH = 8;  per_batch = 288; }
    else                  { CH = 16; per_batch = 160; }
    const int nblk = 4 * per_batch;

    unsigned short* partO  = wt + (size_t)3*64*C_;
    float*          partML = (float*)(partO + (size_t)nblk*4096);

    prep_weights<<<48, 256, 0, stream>>>(wq, wk, wv, wt);
    qkv_mfma_kernel<<<ROWS_/32, 256, 0, stream>>>(x, wt, qb, kb, vtb);
    attn_chunk_kernel<<<nblk, 256, 0, stream>>>(qb, kb, vtb, partO, partML,
                                                CH, per_batch);
    combine_kernel<<<256, 256, 0, stream>>>(partO, partML, out, CH, per_batch);
}